// Round 15
// baseline (308.249 us; speedup 1.0000x reference)
//
#include <hip/hip_runtime.h>

// SIREN MLP fused kernel, MI355X gfx950 — round 15.
// [262144,3] -> sin(30(xW^T+b)) -> 4x sin(30(hW^T+b)) [256x256] -> linear -> [262144,3]
// All global tensors fp32. h kept as fp16 (MFMA operand), fp32 accumulate.
// R15 = R14 per-wave shape at 2x block scale:
//   Resource model (R6/R12/R13): ~124-128 total regs/wave (60 VGPR + 64 AGPR
//   for W) -> 2048-reg file fits exactly 16 waves/CU = 4 waves/SIMD. TLP capped.
//   So scale the BLOCK: BM 128, 1024 threads, 16 waves (8 fgroups x 2 phalves,
//   same 32-feat wave tile). Per-layer fixed phases amortize 2x, W L2 traffic
//   halves, LDS 140KB = 1 block/CU at the same 4 waves/SIMD.
//   + np rotation per wave (npr=(np+wv)&3): decorrelates waves' LDS rows and
//   mixes MFMA/epilogue phases across waves. Legal: np tiles are independent.
//   Numerics per-point identical -> absmax must repeat 0.0009765625.

typedef _Float16 hf8 __attribute__((ext_vector_type(8)));
typedef _Float16 hf4 __attribute__((ext_vector_type(4)));
typedef _Float16 hf2 __attribute__((ext_vector_type(2)));
typedef __fp16   fp16x2 __attribute__((ext_vector_type(2)));   // cvt_pkrtz return type
typedef float floatx4 __attribute__((ext_vector_type(4)));

#define HID 256
#define NHID 4
#define BM 128          // points per block
#define STRIDE 264      // padded LDS row stride (elems): 528B = 4 dwords mod 32 banks
#define THREADS 1024    // 16 waves = 8 feature-groups x 2 point-halves
#define NP 4            // point-tiles per wave (64 pts per half / 16)
#define C_REV 4.774648292756860f   // 30 / (2*pi)
#define WH_ELEMS (NHID*HID*HID)    // 262144
#define WS_HALVES (WH_ELEMS + 3*HID)

// sin(2*pi*r): v_fract -> [0,1) (sin periodic; fract output always in HW range)
__device__ __forceinline__ float sin_rev(float r){
  float f, s;
  asm("v_fract_f32 %0, %1" : "=v"(f) : "v"(r));
  asm("v_sin_f32 %0, %1"   : "=v"(s) : "v"(f));
  return s;
}
__device__ __forceinline__ hf2 pk2(float a, float b){
  const fp16x2 p = __builtin_amdgcn_cvt_pkrtz(a, b);
  return __builtin_bit_cast(hf2, p);
}
__device__ __forceinline__ hf8 ld8h_f32(const float* f){
  const floatx4 a = *(const floatx4*)f;
  const floatx4 b = *(const floatx4*)(f + 4);
  hf8 o;
#pragma unroll
  for (int e = 0; e < 4; ++e){ o[e] = (_Float16)a[e]; o[4+e] = (_Float16)b[e]; }
  return o;
}
__device__ __forceinline__ int hix(int r, int c){ return r*STRIDE + c; }

// ---- prepass: w_hidden, w_final fp32 -> fp16 in ws (unscaled) ----
__global__ void prep_kernel(const float* __restrict__ wh,
                            const float* __restrict__ wfin,
                            _Float16* __restrict__ ws){
  const int i = blockIdx.x*256 + threadIdx.x;
  if (i < WH_ELEMS)            ws[i] = (_Float16)wh[i];
  else if (i < WS_HALVES)      ws[i] = (_Float16)wfin[i - WH_ELEMS];
}

template<bool WS>
__global__ __launch_bounds__(THREADS, 4) void siren_kernel(
    const float* __restrict__ x, const float* __restrict__ w_first,
    const float* __restrict__ b_first, const float* __restrict__ w_hidden,
    const float* __restrict__ b_hidden, const float* __restrict__ w_final,
    const float* __restrict__ b_final, const _Float16* __restrict__ wsh,
    float* __restrict__ out)
{
  __shared__ __align__(16) _Float16 hbuf[2][BM*STRIDE];  // 132 KB double-buffered h (padded)
  __shared__ __align__(16) float    wf[HID*4];           // 4 KB first-layer (w0,w1,w2,b)*C_REV
  __shared__ __align__(16) float    blds[NHID*HID];      // 4 KB hidden biases * C_REV

  const int tid = threadIdx.x;
  const int blk = blockIdx.x;

  if (tid < HID){
    wf[tid*4+0] = w_first[tid*3+0] * C_REV;
    wf[tid*4+1] = w_first[tid*3+1] * C_REV;
    wf[tid*4+2] = w_first[tid*3+2] * C_REV;
    wf[tid*4+3] = b_first[tid]     * C_REV;
  }
  if (tid < NHID*HID)
    blds[tid] = b_hidden[tid] * C_REV;
  __syncthreads();

  // ---- first layer (K=3, VALU): 128 rows x 8 col-strips of 32 ----
  {
    const int row = tid & (BM-1);
    const int cb  = (tid >> 7) * 32;
    const int gr  = blk*BM + row;
    const float x0 = x[gr*3+0];
    const float x1 = x[gr*3+1];
    const float x2 = x[gr*3+2];
#pragma unroll
    for (int g = 0; g < 4; ++g){
      float sv[8];
#pragma unroll
      for (int e = 0; e < 8; ++e){
        const int j = cb + g*8 + e;
        const floatx4 w = *(const floatx4*)(&wf[j*4]);   // wave-uniform broadcast
        float r = w[3];
        r = fmaf(x0, w[0], r);
        r = fmaf(x1, w[1], r);
        r = fmaf(x2, w[2], r);
        sv[e] = sin_rev(r);
      }
      hf8 hv;
#pragma unroll
      for (int p = 0; p < 4; ++p){
        const hf2 pk = pk2(sv[2*p], sv[2*p+1]);
        hv[2*p] = pk[0]; hv[2*p+1] = pk[1];
      }
      *(hf8*)(&hbuf[0][hix(row, cb + g*8)]) = hv;
    }
  }
  __syncthreads();

  // ---- hidden layers: z^T = W.h^T via mfma_f32_16x16x32_f16 ----
  // 16 waves = feature-group fg (0..7, 32 feats) x point-half ph (0..1, 64 pts).
  // A = W rows (m=l&15, k-chunk=(l>>4)*8); B = h^T from LDS (same k map ->
  // k-permutation cancels). D: reg g -> feature (l>>4)*4+g, col -> point l&15.
  const int wv  = tid >> 6;
  const int fg  = wv >> 1;
  const int ph  = wv & 1;
  const int l   = tid & 63;
  const int l15 = l & 15;
  const int l4  = l >> 4;

  const _Float16* rb = &hbuf[0][0];
  _Float16*       wb = &hbuf[1][0];
#pragma unroll 1
  for (int L = 0; L < NHID; ++L){
    hf8   wfr[2][8];
    float bC[2][4];
#pragma unroll
    for (int m2 = 0; m2 < 2; ++m2){
      const int jrow  = fg*32 + m2*16 + l15;
      const int wbase = L*HID*HID + jrow*HID + l4*8;
#pragma unroll
      for (int k = 0; k < 8; ++k){
        if (WS) wfr[m2][k] = *(const hf8*)(wsh + wbase + k*32);   // one dwordx4
        else    wfr[m2][k] = ld8h_f32(w_hidden + wbase + k*32);
      }
      const int j0 = fg*32 + m2*16 + l4*4;
      const floatx4 bb = *(const floatx4*)(&blds[L*HID + j0]);    // one ds_read_b128
#pragma unroll
      for (int g = 0; g < 4; ++g)
        bC[m2][g] = bb[g];
    }

#pragma unroll 2
    for (int np = 0; np < NP; ++np){
      const int npr = (np + wv) & 3;            // per-wave rotation (tiles independent)
      const int r = ph*64 + npr*16 + l15;
      hf8 bh[8];
#pragma unroll
      for (int k = 0; k < 8; ++k)
        bh[k] = *(const hf8*)(rb + hix(r, k*32 + l4*8));
      floatx4 acc0 = {0.f,0.f,0.f,0.f};
      floatx4 acc1 = {0.f,0.f,0.f,0.f};
      __builtin_amdgcn_s_setprio(1);
#pragma unroll
      for (int k = 0; k < 8; ++k){
        acc0 = __builtin_amdgcn_mfma_f32_16x16x32_f16(wfr[0][k], bh[k], acc0, 0, 0, 0);
        acc1 = __builtin_amdgcn_mfma_f32_16x16x32_f16(wfr[1][k], bh[k], acc1, 0, 0, 0);
      }
      __builtin_amdgcn_s_setprio(0);
#pragma unroll
      for (int m2 = 0; m2 < 2; ++m2){
        const floatx4 z = m2 ? acc1 : acc0;
        float sv[4];
#pragma unroll
        for (int g = 0; g < 4; ++g)
          sv[g] = sin_rev(fmaf(z[g], C_REV, bC[m2][g]));
        const hf2 p0 = pk2(sv[0], sv[1]);
        const hf2 p1 = pk2(sv[2], sv[3]);
        hf4 hv; hv[0]=p0[0]; hv[1]=p0[1]; hv[2]=p1[0]; hv[3]=p1[1];
        const int jb = fg*32 + m2*16 + l4*4;
        *(hf4*)(wb + hix(r, jb)) = hv;
      }
    }
    _Float16* t = (_Float16*)rb; rb = wb; wb = t;
    __syncthreads();
  }
  // after 4 layers, h is in hbuf[0] (== rb)

  // ---- final linear (fp32 out): 128 rows x 8-way K-split ----
  {
    const int row = tid >> 3;
    const int q   = tid & 7;
    float s0 = 0.f, s1 = 0.f, s2 = 0.f;
#pragma unroll
    for (int i = 0; i < 4; ++i){
      const int c = q*32 + i*8;
      const hf8 hv = *(const hf8*)(rb + hix(row, c));
      hf8 w0, w1, w2;
      if (WS){
        const _Float16* wfh = wsh + WH_ELEMS;
        w0 = *(const hf8*)(wfh + 0*HID + c);
        w1 = *(const hf8*)(wfh + 1*HID + c);
        w2 = *(const hf8*)(wfh + 2*HID + c);
      } else {
        w0 = ld8h_f32(w_final + 0*HID + c);
        w1 = ld8h_f32(w_final + 1*HID + c);
        w2 = ld8h_f32(w_final + 2*HID + c);
      }
#pragma unroll
      for (int e = 0; e < 8; ++e){
        const float h = (float)hv[e];
        s0 = fmaf(h, (float)w0[e], s0);
        s1 = fmaf(h, (float)w1[e], s1);
        s2 = fmaf(h, (float)w2[e], s2);
      }
    }
    s0 += __shfl_xor(s0, 1); s0 += __shfl_xor(s0, 2); s0 += __shfl_xor(s0, 4);
    s1 += __shfl_xor(s1, 1); s1 += __shfl_xor(s1, 2); s1 += __shfl_xor(s1, 4);
    s2 += __shfl_xor(s2, 1); s2 += __shfl_xor(s2, 2); s2 += __shfl_xor(s2, 4);
    if (q == 0){
      const int gr = blk*BM + row;
      out[gr*3+0] = s0 + b_final[0];
      out[gr*3+1] = s1 + b_final[1];
      out[gr*3+2] = s2 + b_final[2];
    }
  }
}

extern "C" void kernel_launch(void* const* d_in, const int* in_sizes, int n_in,
                              void* d_out, int out_size, void* d_ws, size_t ws_size,
                              hipStream_t stream) {
  const float* x        = (const float*)d_in[0];
  const float* w_first  = (const float*)d_in[1];
  const float* b_first  = (const float*)d_in[2];
  const float* w_hidden = (const float*)d_in[3];
  const float* b_hidden = (const float*)d_in[4];
  const float* w_final  = (const float*)d_in[5];
  const float* b_final  = (const float*)d_in[6];
  float* out = (float*)d_out;
  _Float16* wsh = (_Float16*)d_ws;

  const int npts = in_sizes[0] / 3;
  const int grid = npts / BM;   // 2048
  const bool use_ws = (ws_size >= (size_t)WS_HALVES * sizeof(_Float16));

  if (use_ws){
    const int pgrid = (WS_HALVES + 255) / 256;
    hipLaunchKernelGGL(prep_kernel, dim3(pgrid), dim3(256), 0, stream,
                       w_hidden, w_final, wsh);
    hipLaunchKernelGGL(siren_kernel<true>, dim3(grid), dim3(THREADS), 0, stream,
                       x, w_first, b_first, w_hidden, b_hidden, w_final, b_final,
                       wsh, out);
  } else {
    hipLaunchKernelGGL(siren_kernel<false>, dim3(grid), dim3(THREADS), 0, stream,
                       x, w_first, b_first, w_hidden, b_hidden, w_final, b_final,
                       wsh, out);
  }
}

// Round 16
// 267.663 us; speedup vs baseline: 1.1516x; 1.1516x over previous
//
#include <hip/hip_runtime.h>

// SIREN MLP fused kernel, MI355X gfx950 — round 16.
// [262144,3] -> sin(30(xW^T+b)) -> 4x sin(30(hW^T+b)) [256x256] -> linear -> [262144,3]
// All global tensors fp32. h kept as fp16 (MFMA operand), fp32 accumulate.
// R16 = R14 (274us best) + schedule-only changes (numerics byte-identical):
//   R15 lesson: BM=128/16 waves -> 1 block/CU, whole-CU barrier drains, 308us.
//   Model: ~128 total regs/wave caps 16 waves/CU; ~28% of cycles are no-issue
//   (barrier drains + W L2 latency + lockstep phases).
//   1) W software-pipeline: layer L+1's W (16 dwordx4, global->reg) issued
//      after layer L's np loop, BEFORE the barrier — vmcnt stays outstanding
//      across s_barrier (no LDS dependence -> no drain), hiding W latency
//      under the barrier + next layer's early phase. Layer-0 W issues before
//      the first-layer VALU phase. sched_barrier(0) fences keep the prefetch
//      out of the np loop (would double W liveness -> spill).
//   2) np rotation npr=(np+wv)&3: decorrelates waves' LDS rows and staggers
//      phases across the 2 resident blocks (R15 idea, first A/B on good geom).

typedef _Float16 hf8 __attribute__((ext_vector_type(8)));
typedef _Float16 hf4 __attribute__((ext_vector_type(4)));
typedef _Float16 hf2 __attribute__((ext_vector_type(2)));
typedef __fp16   fp16x2 __attribute__((ext_vector_type(2)));   // cvt_pkrtz return type
typedef float floatx4 __attribute__((ext_vector_type(4)));

#define HID 256
#define NHID 4
#define BM 64           // points per block
#define STRIDE 264      // padded LDS row stride (elems): 528B = 4 dwords mod 32 banks
#define THREADS 512     // 8 waves; wave w owns output features [32w, 32w+32)
#define NP (BM/16)      // 4 point-tiles per wave
#define C_REV 4.774648292756860f   // 30 / (2*pi)
#define WH_ELEMS (NHID*HID*HID)    // 262144
#define WS_HALVES (WH_ELEMS + 3*HID)

// sin(2*pi*r): v_fract -> [0,1) (sin periodic; fract output always in HW range)
__device__ __forceinline__ float sin_rev(float r){
  float f, s;
  asm("v_fract_f32 %0, %1" : "=v"(f) : "v"(r));
  asm("v_sin_f32 %0, %1"   : "=v"(s) : "v"(f));
  return s;
}
__device__ __forceinline__ hf2 pk2(float a, float b){
  const fp16x2 p = __builtin_amdgcn_cvt_pkrtz(a, b);
  return __builtin_bit_cast(hf2, p);
}
__device__ __forceinline__ hf8 ld8h_f32(const float* f){
  const floatx4 a = *(const floatx4*)f;
  const floatx4 b = *(const floatx4*)(f + 4);
  hf8 o;
#pragma unroll
  for (int e = 0; e < 4; ++e){ o[e] = (_Float16)a[e]; o[4+e] = (_Float16)b[e]; }
  return o;
}
__device__ __forceinline__ int hix(int r, int c){ return r*STRIDE + c; }

// ---- prepass: w_hidden, w_final fp32 -> fp16 in ws (unscaled) ----
__global__ void prep_kernel(const float* __restrict__ wh,
                            const float* __restrict__ wfin,
                            _Float16* __restrict__ ws){
  const int i = blockIdx.x*256 + threadIdx.x;
  if (i < WH_ELEMS)            ws[i] = (_Float16)wh[i];
  else if (i < WS_HALVES)      ws[i] = (_Float16)wfin[i - WH_ELEMS];
}

template<bool WS>
__global__ __launch_bounds__(THREADS, 4) void siren_kernel(
    const float* __restrict__ x, const float* __restrict__ w_first,
    const float* __restrict__ b_first, const float* __restrict__ w_hidden,
    const float* __restrict__ b_hidden, const float* __restrict__ w_final,
    const float* __restrict__ b_final, const _Float16* __restrict__ wsh,
    float* __restrict__ out)
{
  __shared__ __align__(16) _Float16 hbuf[2][BM*STRIDE];  // 66 KB double-buffered h (padded rows)
  __shared__ __align__(16) float    wf[HID*4];           // 4 KB first-layer (w0,w1,w2,b)*C_REV
  __shared__ __align__(16) float    blds[NHID*HID];      // 4 KB hidden biases * C_REV

  const int tid = threadIdx.x;
  const int blk = blockIdx.x;

  const int wv  = tid >> 6;
  const int l   = tid & 63;
  const int l15 = l & 15;
  const int l4  = l >> 4;

  if (tid < HID){
    wf[tid*4+0] = w_first[tid*3+0] * C_REV;
    wf[tid*4+1] = w_first[tid*3+1] * C_REV;
    wf[tid*4+2] = w_first[tid*3+2] * C_REV;
    wf[tid*4+3] = b_first[tid]     * C_REV;
  }
#pragma unroll
  for (int i = tid; i < NHID*HID; i += THREADS)
    blds[i] = b_hidden[i] * C_REV;
  __syncthreads();

  // ---- prologue: issue layer-0 W loads (overlap with first-layer VALU) ----
  hf8   wfr[2][8];
  float bC[2][4];
#pragma unroll
  for (int m2 = 0; m2 < 2; ++m2){
    const int jrow  = wv*32 + m2*16 + l15;
    const int wbase = jrow*HID + l4*8;
#pragma unroll
    for (int k = 0; k < 8; ++k){
      if (WS) wfr[m2][k] = *(const hf8*)(wsh + wbase + k*32);
      else    wfr[m2][k] = ld8h_f32(w_hidden + wbase + k*32);
    }
    const int j0 = wv*32 + m2*16 + l4*4;
    const floatx4 bb = *(const floatx4*)(&blds[j0]);
#pragma unroll
    for (int g = 0; g < 4; ++g) bC[m2][g] = bb[g];
  }
  __builtin_amdgcn_sched_barrier(0);   // keep W0 loads above first-layer compute

  // ---- first layer (K=3, VALU): 64 rows x 8 col-strips of 32 ----
  {
    const int row = tid & (BM-1);
    const int cb  = (tid >> 6) * 32;
    const int gr  = blk*BM + row;
    const float x0 = x[gr*3+0];
    const float x1 = x[gr*3+1];
    const float x2 = x[gr*3+2];
#pragma unroll
    for (int g = 0; g < 4; ++g){
      float sv[8];
#pragma unroll
      for (int e = 0; e < 8; ++e){
        const int j = cb + g*8 + e;
        const floatx4 w = *(const floatx4*)(&wf[j*4]);   // wave-uniform broadcast
        float r = w[3];
        r = fmaf(x0, w[0], r);
        r = fmaf(x1, w[1], r);
        r = fmaf(x2, w[2], r);
        sv[e] = sin_rev(r);
      }
      hf8 hv;
#pragma unroll
      for (int p = 0; p < 4; ++p){
        const hf2 pk = pk2(sv[2*p], sv[2*p+1]);
        hv[2*p] = pk[0]; hv[2*p+1] = pk[1];
      }
      *(hf8*)(&hbuf[0][hix(row, cb + g*8)]) = hv;
    }
  }
  __syncthreads();

  // ---- hidden layers: z^T = W.h^T via mfma_f32_16x16x32_f16 ----
  // A = W rows (m=l&15, k-chunk=(l>>4)*8); B = h^T from LDS (same k map ->
  // k-permutation cancels). D: reg g -> feature (l>>4)*4+g, col -> point l&15.
  const _Float16* rb = &hbuf[0][0];
  _Float16*       wb = &hbuf[1][0];
#pragma unroll 1
  for (int L = 0; L < NHID; ++L){
#pragma unroll 2
    for (int np = 0; np < NP; ++np){
      const int npr = (np + wv) & 3;            // per-wave rotation (tiles independent)
      const int r = npr*16 + l15;
      hf8 bh[8];
#pragma unroll
      for (int k = 0; k < 8; ++k)
        bh[k] = *(const hf8*)(rb + hix(r, k*32 + l4*8));   // affine -> offset imm
      floatx4 acc0 = {0.f,0.f,0.f,0.f};
      floatx4 acc1 = {0.f,0.f,0.f,0.f};
      __builtin_amdgcn_s_setprio(1);
#pragma unroll
      for (int k = 0; k < 8; ++k){
        acc0 = __builtin_amdgcn_mfma_f32_16x16x32_f16(wfr[0][k], bh[k], acc0, 0, 0, 0);
        acc1 = __builtin_amdgcn_mfma_f32_16x16x32_f16(wfr[1][k], bh[k], acc1, 0, 0, 0);
      }
      __builtin_amdgcn_s_setprio(0);
#pragma unroll
      for (int m2 = 0; m2 < 2; ++m2){
        const floatx4 z = m2 ? acc1 : acc0;
        float sv[4];
#pragma unroll
        for (int g = 0; g < 4; ++g)
          sv[g] = sin_rev(fmaf(z[g], C_REV, bC[m2][g]));
        const hf2 p0 = pk2(sv[0], sv[1]);
        const hf2 p1 = pk2(sv[2], sv[3]);
        hf4 hv; hv[0]=p0[0]; hv[1]=p0[1]; hv[2]=p1[0]; hv[3]=p1[1];
        const int jb = wv*32 + m2*16 + l4*4;
        *(hf4*)(wb + hix(r, jb)) = hv;
      }
    }

    // ---- prefetch next layer's W/bias BEFORE the barrier (vmcnt spans it) ----
    __builtin_amdgcn_sched_barrier(0);   // don't hoist into np loop (liveness)
    if (L + 1 < NHID){
#pragma unroll
      for (int m2 = 0; m2 < 2; ++m2){
        const int jrow  = wv*32 + m2*16 + l15;
        const int wbase = (L+1)*HID*HID + jrow*HID + l4*8;
#pragma unroll
        for (int k = 0; k < 8; ++k){
          if (WS) wfr[m2][k] = *(const hf8*)(wsh + wbase + k*32);
          else    wfr[m2][k] = ld8h_f32(w_hidden + wbase + k*32);
        }
        const int j0 = wv*32 + m2*16 + l4*4;
        const floatx4 bb = *(const floatx4*)(&blds[(L+1)*HID + j0]);
#pragma unroll
        for (int g = 0; g < 4; ++g) bC[m2][g] = bb[g];
      }
    }
    _Float16* t = (_Float16*)rb; rb = wb; wb = t;
    __syncthreads();
  }
  // after 4 layers, h is in hbuf[0] (== rb)

  // ---- final linear (fp32 out): 64 rows x 8-way K-split ----
  {
    const int row = tid >> 3;
    const int q   = tid & 7;
    float s0 = 0.f, s1 = 0.f, s2 = 0.f;
#pragma unroll
    for (int i = 0; i < 4; ++i){
      const int c = q*32 + i*8;
      const hf8 hv = *(const hf8*)(rb + hix(row, c));
      hf8 w0, w1, w2;
      if (WS){
        const _Float16* wfh = wsh + WH_ELEMS;
        w0 = *(const hf8*)(wfh + 0*HID + c);
        w1 = *(const hf8*)(wfh + 1*HID + c);
        w2 = *(const hf8*)(wfh + 2*HID + c);
      } else {
        w0 = ld8h_f32(w_final + 0*HID + c);
        w1 = ld8h_f32(w_final + 1*HID + c);
        w2 = ld8h_f32(w_final + 2*HID + c);
      }
#pragma unroll
      for (int e = 0; e < 8; ++e){
        const float h = (float)hv[e];
        s0 = fmaf(h, (float)w0[e], s0);
        s1 = fmaf(h, (float)w1[e], s1);
        s2 = fmaf(h, (float)w2[e], s2);
      }
    }
    s0 += __shfl_xor(s0, 1); s0 += __shfl_xor(s0, 2); s0 += __shfl_xor(s0, 4);
    s1 += __shfl_xor(s1, 1); s1 += __shfl_xor(s1, 2); s1 += __shfl_xor(s1, 4);
    s2 += __shfl_xor(s2, 1); s2 += __shfl_xor(s2, 2); s2 += __shfl_xor(s2, 4);
    if (q == 0){
      const int gr = blk*BM + row;
      out[gr*3+0] = s0 + b_final[0];
      out[gr*3+1] = s1 + b_final[1];
      out[gr*3+2] = s2 + b_final[2];
    }
  }
}

extern "C" void kernel_launch(void* const* d_in, const int* in_sizes, int n_in,
                              void* d_out, int out_size, void* d_ws, size_t ws_size,
                              hipStream_t stream) {
  const float* x        = (const float*)d_in[0];
  const float* w_first  = (const float*)d_in[1];
  const float* b_first  = (const float*)d_in[2];
  const float* w_hidden = (const float*)d_in[3];
  const float* b_hidden = (const float*)d_in[4];
  const float* w_final  = (const float*)d_in[5];
  const float* b_final  = (const float*)d_in[6];
  float* out = (float*)d_out;
  _Float16* wsh = (_Float16*)d_ws;

  const int npts = in_sizes[0] / 3;
  const int grid = npts / BM;   // 4096
  const bool use_ws = (ws_size >= (size_t)WS_HALVES * sizeof(_Float16));

  if (use_ws){
    const int pgrid = (WS_HALVES + 255) / 256;
    hipLaunchKernelGGL(prep_kernel, dim3(pgrid), dim3(256), 0, stream,
                       w_hidden, w_final, wsh);
    hipLaunchKernelGGL(siren_kernel<true>, dim3(grid), dim3(THREADS), 0, stream,
                       x, w_first, b_first, w_hidden, b_hidden, w_final, b_final,
                       wsh, out);
  } else {
    hipLaunchKernelGGL(siren_kernel<false>, dim3(grid), dim3(THREADS), 0, stream,
                       x, w_first, b_first, w_hidden, b_hidden, w_final, b_final,
                       wsh, out);
  }
}